// Round 17
// baseline (461.697 us; speedup 1.0000x reference)
//
#include <hip/hip_runtime.h>

// Problem constants (fixed by the reference)
#define N_NODES 100000
#define N_EDGES 1600000
#define DIM     128
#define EDIM    16
#define NLAYERS 5

typedef unsigned short ushort_t;
typedef short bf16x8 __attribute__((ext_vector_type(8)));   // 8 bf16 in 4 VGPRs
typedef float f32x4  __attribute__((ext_vector_type(4)));

__device__ __forceinline__ ushort_t f2bf(float f) {
    union { float f; unsigned int i; } c; c.f = f;
    unsigned int r = c.i + 0x7fffu + ((c.i >> 16) & 1u);   // RNE
    return (ushort_t)(r >> 16);
}
__device__ __forceinline__ float lo_bf(unsigned int w) {
    union { unsigned int i; float f; } c; c.i = w << 16; return c.f;
}
__device__ __forceinline__ float hi_bf(unsigned int w) {
    union { unsigned int i; float f; } c; c.i = w & 0xffff0000u; return c.f;
}
__device__ __forceinline__ unsigned int pk_bf16(float lo, float hi) {
    unsigned int r;
    asm("v_cvt_pk_bf16_f32 %0, %1, %2" : "=v"(r) : "v"(lo), "v"(hi));
    return r;
}
__device__ __forceinline__ bf16x8 pk8(f32x4 a, f32x4 b) {
    union { unsigned int w[4]; bf16x8 v; } c;
    c.w[0] = pk_bf16(a[0], a[1]); c.w[1] = pk_bf16(a[2], a[3]);
    c.w[2] = pk_bf16(b[0], b[1]); c.w[3] = pk_bf16(b[2], b[3]);
    return c.v;
}
// silu via fast hw reciprocal (~1ulp; noise vs bf16 rounding)
__device__ __forceinline__ float fast_silu(float x) {
    return x * __builtin_amdgcn_rcpf(1.0f + __expf(-x));
}
// Wave-local LDS ordering: drain ds ops + block compiler motion across.
// Only waits lgkmcnt -- outstanding GLOBAL loads issued earlier in program
// order (the staged prefetches) remain in flight across this.
__device__ __forceinline__ void lds_fence() {
    asm volatile("s_waitcnt lgkmcnt(0)" ::: "memory");
    __builtin_amdgcn_sched_barrier(0);
}

// ---------------------------------------------------------------------------
// Swizzle weights into bf16 B-fragments (B-frag of M == A-frag of M^T).
// w1s: [layer][t(0..8)][lane][8]; t0..3 = W1a, t4..7 = W1b, t8 = W1c (pad).
// w2s: [layer][lane][8]; K padded 16->32 (zeros).
// Composite weights (R14, verified): Wc_{l+1} = W2_l @ W1c_{l+1},
// bc_{l+1} = W1c_{l+1}^T b2_l + b1_{l+1}.
// wcs: [4][lane][8] frags for global layers 1..4; bcs: [4][16] fp32.
// ---------------------------------------------------------------------------
__global__ void swizzle_weights(const float* __restrict__ eW1,
                                const float* __restrict__ eW2,
                                const float* __restrict__ eb1,
                                const float* __restrict__ eb2,
                                ushort_t* __restrict__ w1s,
                                ushort_t* __restrict__ w2s,
                                ushort_t* __restrict__ wcs,
                                float* __restrict__ bcs) {
    int id = blockIdx.x * 256 + threadIdx.x;
    const int base = NLAYERS * 10 * 64;
    if (id < base) {
        int lane = id & 63;
        int t10 = id >> 6;
        int layer = t10 / 10, t = t10 % 10;
        int n = lane & 15, quad = lane >> 4;
        if (t < 9) {
            ushort_t* dst = w1s + ((size_t)(layer * 9 + t) * 64 + lane) * 8;
            #pragma unroll
            for (int j = 0; j < 8; ++j) {
                int k = t * 32 + quad * 8 + j;
                dst[j] = (k < 2 * DIM + EDIM)
                           ? f2bf(eW1[((size_t)layer * 272 + k) * 16 + n])
                           : (ushort_t)0;
            }
        } else {
            ushort_t* dst = w2s + ((size_t)layer * 64 + lane) * 8;
            #pragma unroll
            for (int j = 0; j < 8; ++j) {
                int k = quad * 8 + j;
                dst[j] = (k < EDIM) ? f2bf(eW2[((size_t)layer * 16 + k) * 16 + n])
                                    : (ushort_t)0;
            }
        }
    } else if (id < base + 4 * 64) {            // composite weight frags
        int id2 = id - base;
        int l = id2 >> 6;                       // 0..3 -> global layer l+1
        int lane = id2 & 63, n = lane & 15, quad = lane >> 4;
        ushort_t* dst = wcs + ((size_t)l * 64 + lane) * 8;
        #pragma unroll
        for (int j = 0; j < 8; ++j) {
            int r = quad * 8 + j;               // h-feature (contraction) index
            float acc = 0.f;
            if (r < EDIM)
                for (int k = 0; k < EDIM; ++k)
                    acc += eW2[((size_t)l * 16 + r) * 16 + k]
                         * eW1[((size_t)(l + 1) * 272 + 256 + k) * 16 + n];
            dst[j] = (r < EDIM) ? f2bf(acc) : (ushort_t)0;
        }
    } else if (id < base + 4 * 64 + 64) {       // composite biases
        int id2 = id - base - 4 * 64;           // 0..63
        int l = id2 >> 4, n = id2 & 15;         // global layer l+1
        float acc = eb1[(l + 1) * 16 + n];
        for (int k = 0; k < EDIM; ++k)
            acc += eb2[l * 16 + k] * eW1[((size_t)(l + 1) * 272 + 256 + k) * 16 + n];
        bcs[l * 16 + n] = acc;
    }
}

// ---------------------------------------------------------------------------
// Fused LayerNorm chain + per-node projections (unchanged from R5).
// ---------------------------------------------------------------------------
__global__ __launch_bounds__(256) void ln_uv(
        const float* __restrict__ sin, float* __restrict__ sout,
        const float* __restrict__ lnw, const float* __restrict__ lnb, // [5][128]
        const ushort_t* __restrict__ w1s,                             // all layers
        ushort_t* __restrict__ u_buf, ushort_t* __restrict__ v_buf,
        int l0, int l1, int lstr) {
    const int wv = threadIdx.x >> 6, lane = threadIdx.x & 63;
    const int m = lane & 15, quad = lane >> 4;
    const int tile = blockIdx.x * 4 + wv;
    if (tile >= N_NODES / 16) return;           // 6250 tiles exactly
    const int node = tile * 16 + m;

    float x[32];
    {
        const float* row = sin + (size_t)node * DIM + quad * 8;
        #pragma unroll
        for (int t = 0; t < 4; ++t) {
            f32x4 a = *(const f32x4*)(row + t * 32);
            f32x4 b = *(const f32x4*)(row + t * 32 + 4);
            #pragma unroll
            for (int j = 0; j < 4; ++j) { x[t * 8 + j] = a[j]; x[t * 8 + 4 + j] = b[j]; }
        }
    }

    for (int li = l0; li < l1; ++li) {
        float s = 0.f;
        #pragma unroll
        for (int k = 0; k < 32; ++k) s += x[k];
        s += __shfl_xor(s, 16); s += __shfl_xor(s, 32);
        float mu = s * (1.0f / DIM);
        float ss = 0.f;
        #pragma unroll
        for (int k = 0; k < 32; ++k) { float d = x[k] - mu; ss += d * d; }
        ss += __shfl_xor(ss, 16); ss += __shfl_xor(ss, 32);
        float rs = rsqrtf(ss * (1.0f / DIM) + 1e-5f);

        const float* w = lnw + (size_t)li * DIM + quad * 8;
        const float* b = lnb + (size_t)li * DIM + quad * 8;
        f32x4 au = {0.f, 0.f, 0.f, 0.f}, av = {0.f, 0.f, 0.f, 0.f};
        #pragma unroll
        for (int t = 0; t < 4; ++t) {
            f32x4 wa = *(const f32x4*)(w + t * 32), wb = *(const f32x4*)(w + t * 32 + 4);
            f32x4 ba = *(const f32x4*)(b + t * 32), bb = *(const f32x4*)(b + t * 32 + 4);
            #pragma unroll
            for (int j = 0; j < 4; ++j) {
                x[t * 8 + j]     = (x[t * 8 + j]     - mu) * rs * wa[j] + ba[j];
                x[t * 8 + 4 + j] = (x[t * 8 + 4 + j] - mu) * rs * wb[j] + bb[j];
            }
            f32x4 ya, yb;
            #pragma unroll
            for (int j = 0; j < 4; ++j) { ya[j] = x[t * 8 + j]; yb[j] = x[t * 8 + 4 + j]; }
            bf16x8 af = pk8(ya, yb);
            bf16x8 bu = *(const bf16x8*)(w1s + ((size_t)(li * 9 + t)     * 64 + lane) * 8);
            bf16x8 bv = *(const bf16x8*)(w1s + ((size_t)(li * 9 + 4 + t) * 64 + lane) * 8);
            au = __builtin_amdgcn_mfma_f32_16x16x32_bf16(bu, af, au, 0, 0, 0);
            av = __builtin_amdgcn_mfma_f32_16x16x32_bf16(bv, af, av, 0, 0, 0);
        }
        size_t rec = ((size_t)node * lstr + (li - l0)) * EDIM + quad * 4;
        uint2 tu; tu.x = pk_bf16(au[0], au[1]); tu.y = pk_bf16(au[2], au[3]);
        uint2 tv; tv.x = pk_bf16(av[0], av[1]); tv.y = pk_bf16(av[2], av[3]);
        *(uint2*)(u_buf + rec) = tu;
        *(uint2*)(v_buf + rec) = tv;
    }

    float* orow = sout + (size_t)node * DIM + quad * 8;
    #pragma unroll
    for (int t = 0; t < 4; ++t) {
        f32x4 a, b;
        #pragma unroll
        for (int j = 0; j < 4; ++j) { a[j] = x[t * 8 + j]; b[j] = x[t * 8 + 4 + j]; }
        *(f32x4*)(orow + t * 32) = a;
        *(f32x4*)(orow + t * 32 + 4) = b;
    }
}

// ---------------------------------------------------------------------------
// FUSED edge pass, composed weights (R14) + 3-DEEP staged prefetch.
// R14 counters showed: conflicts halved, chain halved, time -5% only =>
// latency-bound on the random u/v gathers (~3.9K cy/iter vs ~1K compute).
// Three register stages A/B/C rotate: the gathers for tile t+3s are issued
// right after tile t's compute -> ~2.5 iterations of latency cover
// (T = max(C, L/3) instead of L/2). No copies: loop unrolled by 3 with
// statically-named stages (rule: no runtime-indexed reg arrays).
// In-place safe: in/out buffers distinct in fused path; in the NL=1 path
// each tile's prefetch-read precedes its own (same-wave) store.
// ---------------------------------------------------------------------------
template<int NL>
__global__ __launch_bounds__(256) void edge_fused(
        const float* __restrict__ ea_in, float* __restrict__ ea_out,
        const int* __restrict__ ei,
        const ushort_t* __restrict__ u_buf, const ushort_t* __restrict__ v_buf,
        const ushort_t* __restrict__ w1s, const ushort_t* __restrict__ w2s,
        const ushort_t* __restrict__ wcs, const float* __restrict__ bcs,
        const float* __restrict__ eb1, const float* __restrict__ eb2,
        int l0) {
    __shared__ ushort_t tbH[4][16 * 24];   // per-wave, 48B rows (16B-aligned reads)
    const int wv = threadIdx.x >> 6, lane = threadIdx.x & 63;
    const int m = lane & 15, quad = lane >> 4;

    // weight fragments: layer-0 W1c, composite Wc for l=1..NL-1, final W2
    const bf16x8 w1f0 = *(const bf16x8*)(w1s + (((size_t)l0 * 9 + 8) * 64 + lane) * 8);
    const bf16x8 w2f  = *(const bf16x8*)(w2s + ((size_t)(l0 + NL - 1) * 64 + lane) * 8);
    bf16x8 wcf[NL > 1 ? NL - 1 : 1];
    #pragma unroll
    for (int l = 1; l < NL; ++l)
        wcf[l - 1] = *(const bf16x8*)(wcs + ((size_t)(l0 + l - 1) * 64 + lane) * 8);
    f32x4 bx[NL], b2v;
    #pragma unroll
    for (int r = 0; r < 4; ++r) {
        bx[0][r] = eb1[l0 * EDIM + quad * 4 + r];
        b2v[r]   = eb2[(l0 + NL - 1) * EDIM + quad * 4 + r];
    }
    #pragma unroll
    for (int l = 1; l < NL; ++l)
        #pragma unroll
        for (int r = 0; r < 4; ++r)
            bx[l][r] = bcs[(l0 + l - 1) * EDIM + quad * 4 + r];

    ushort_t* tlH = tbH[wv];
    const bf16x8 zf = {0, 0, 0, 0, 0, 0, 0, 0};
    const f32x4 z4 = {0.f, 0.f, 0.f, 0.f};
    const int nTiles = N_EDGES / 64;
    const int stride = gridDim.x;
    const int t0 = blockIdx.x;
    if (t0 >= nTiles) return;
    const int eoff = wv * 16 + m;

    // ---- 3 register stages (statically named; no runtime indexing)
    uint2 guA[NL], gvA[NL]; f32x4 eaAa, eaAb;
    uint2 guB[NL], gvB[NL]; f32x4 eaBa, eaBb;
    uint2 guC[NL], gvC[NL]; f32x4 eaCa, eaCb;
    int esA, edA, esB, edB, esC, edC;

#define CLAMPT(t) ((t) < nTiles ? (t) : t0)
#define LOAD_EI(S, t) do { int _e = (t) * 64 + eoff;                         \
        es##S = ei[_e]; ed##S = ei[N_EDGES + _e]; } while (0)
#define LOAD_GA(S) do { _Pragma("unroll")                                    \
    for (int _l = 0; _l < NL; ++_l) {                                        \
        gu##S[_l] = *(const uint2*)(u_buf + ((size_t)es##S * NL + _l) * EDIM + quad * 4); \
        gv##S[_l] = *(const uint2*)(v_buf + ((size_t)ed##S * NL + _l) * EDIM + quad * 4); \
    } } while (0)
#define LOAD_EA(S, t) do { ea##S##a = z4; ea##S##b = z4; if (quad < 2) {     \
        const float* _p = ea_in + (size_t)((t) * 64 + eoff) * EDIM + quad * 8; \
        ea##S##a = *(const f32x4*)_p; ea##S##b = *(const f32x4*)(_p + 4); } } while (0)
#define COMPUTE_STORE(S, tv) do {                                            \
    f32x4 hv;                                                                \
    {   bf16x8 af = zf;                                                      \
        if (quad < 2) af = pk8(ea##S##a, ea##S##b);                          \
        f32x4 acc = __builtin_amdgcn_mfma_f32_16x16x32_bf16(w1f0, af, z4, 0, 0, 0); \
        hv[0] = fast_silu(acc[0] + lo_bf(gu##S[0].x) + lo_bf(gv##S[0].x) + bx[0][0]); \
        hv[1] = fast_silu(acc[1] + hi_bf(gu##S[0].x) + hi_bf(gv##S[0].x) + bx[0][1]); \
        hv[2] = fast_silu(acc[2] + lo_bf(gu##S[0].y) + lo_bf(gv##S[0].y) + bx[0][2]); \
        hv[3] = fast_silu(acc[3] + hi_bf(gu##S[0].y) + hi_bf(gv##S[0].y) + bx[0][3]); \
    }                                                                        \
    _Pragma("unroll")                                                        \
    for (int _l = 1; _l < NL; ++_l) {                                        \
        uint2 hw; hw.x = pk_bf16(hv[0], hv[1]); hw.y = pk_bf16(hv[2], hv[3]); \
        *(uint2*)(tlH + m * 24 + quad * 4) = hw;                             \
        lds_fence();                                                         \
        bf16x8 hf = zf;                                                      \
        if (quad < 2) hf = *(const bf16x8*)(tlH + m * 24 + quad * 8);        \
        f32x4 acc = __builtin_amdgcn_mfma_f32_16x16x32_bf16(wcf[_l - 1], hf, z4, 0, 0, 0); \
        hv[0] = fast_silu(acc[0] + lo_bf(gu##S[_l].x) + lo_bf(gv##S[_l].x) + bx[_l][0]); \
        hv[1] = fast_silu(acc[1] + hi_bf(gu##S[_l].x) + hi_bf(gv##S[_l].x) + bx[_l][1]); \
        hv[2] = fast_silu(acc[2] + lo_bf(gu##S[_l].y) + lo_bf(gv##S[_l].y) + bx[_l][2]); \
        hv[3] = fast_silu(acc[3] + hi_bf(gu##S[_l].y) + hi_bf(gv##S[_l].y) + bx[_l][3]); \
    }                                                                        \
    f32x4 y;                                                                 \
    {   uint2 hw; hw.x = pk_bf16(hv[0], hv[1]); hw.y = pk_bf16(hv[2], hv[3]); \
        *(uint2*)(tlH + m * 24 + quad * 4) = hw;                             \
        lds_fence();                                                         \
        bf16x8 hf = zf;                                                      \
        if (quad < 2) hf = *(const bf16x8*)(tlH + m * 24 + quad * 8);        \
        f32x4 acc2 = __builtin_amdgcn_mfma_f32_16x16x32_bf16(w2f, hf, z4, 0, 0, 0); \
        y[0] = acc2[0] + b2v[0]; y[1] = acc2[1] + b2v[1];                    \
        y[2] = acc2[2] + b2v[2]; y[3] = acc2[3] + b2v[3];                    \
    }                                                                        \
    *(f32x4*)(ea_out + (size_t)((tv) * 64 + eoff) * EDIM + quad * 4) = y;    \
    } while (0)

    // ---- prologue: fill stages A,B,C (tiles t0, t0+s, t0+2s); then point
    // the ei slots 3 tiles ahead so each stage's reload address is resolved
    // ~3 iterations before it is needed.
    LOAD_EI(A, t0);
    LOAD_EI(B, CLAMPT(t0 + stride));
    LOAD_EI(C, CLAMPT(t0 + 2 * stride));
    LOAD_GA(A); LOAD_EA(A, t0);
    LOAD_GA(B); LOAD_EA(B, CLAMPT(t0 + stride));
    LOAD_GA(C); LOAD_EA(C, CLAMPT(t0 + 2 * stride));
    LOAD_EI(A, CLAMPT(t0 + 3 * stride));
    LOAD_EI(B, CLAMPT(t0 + 4 * stride));
    LOAD_EI(C, CLAMPT(t0 + 5 * stride));

    // ---- main loop, unrolled x3 over the stage roles
    int tile = t0;
    for (;;) {
        COMPUTE_STORE(A, tile);
        LOAD_GA(A); LOAD_EA(A, CLAMPT(tile + 3 * stride));
        LOAD_EI(A, CLAMPT(tile + 6 * stride));
        tile += stride; if (tile >= nTiles) break;

        COMPUTE_STORE(B, tile);
        LOAD_GA(B); LOAD_EA(B, CLAMPT(tile + 3 * stride));
        LOAD_EI(B, CLAMPT(tile + 6 * stride));
        tile += stride; if (tile >= nTiles) break;

        COMPUTE_STORE(C, tile);
        LOAD_GA(C); LOAD_EA(C, CLAMPT(tile + 3 * stride));
        LOAD_EI(C, CLAMPT(tile + 6 * stride));
        tile += stride; if (tile >= nTiles) break;
    }
#undef CLAMPT
#undef LOAD_EI
#undef LOAD_GA
#undef LOAD_EA
#undef COMPUTE_STORE
}

// ---------------------------------------------------------------------------
extern "C" void kernel_launch(void* const* d_in, const int* in_sizes, int n_in,
                              void* d_out, int out_size, void* d_ws, size_t ws_size,
                              hipStream_t stream) {
    const float* s_in  = (const float*)d_in[0];     // [N][128] fp32
    const int*   ei    = (const int*)d_in[1];       // [2][E] int32
    const float* ea_in = (const float*)d_in[2];     // [E][16] fp32
    // d_in[3] = batch: dead
    const float* lnw = (const float*)d_in[4];
    const float* lnb = (const float*)d_in[5];
    const float* eW1 = (const float*)d_in[6];       // [5][272][16]
    const float* eb1 = (const float*)d_in[7];
    const float* eW2 = (const float*)d_in[8];       // [5][16][16]
    const float* eb2 = (const float*)d_in[9];
    // d_in[10..13]: dead (node MLP output discarded)

    float* out_s  = (float*)d_out;                          // [N][128]
    float* out_ea = (float*)d_out + (size_t)N_NODES * DIM;  // [E][16]

    ushort_t* w1s = (ushort_t*)d_ws;                     // 5*9*64*8 = 23040 elems
    ushort_t* w2s = w1s + (size_t)NLAYERS * 9 * 64 * 8;  // 5*64*8 = 2560 elems
    ushort_t* wcs = w2s + (size_t)NLAYERS * 64 * 8;      // 4*64*8 = 2048 elems
    float*    bcs = (float*)(wcs + 4 * 64 * 8);          // 64 floats = 128 elems
    ushort_t* uv0 = wcs + 4 * 64 * 8 + 128;
    const size_t wWords  = (size_t)NLAYERS * 10 * 64 * 8 + 4 * 64 * 8 + 128;
    const size_t uvLayer = (size_t)N_NODES * EDIM;           // 1.6M elems
    const size_t needFused = (wWords + 2 * (size_t)NLAYERS * uvLayer) * 2;
    const int lnGrid = (N_NODES / 16 + 3) / 4;   // 1563
    // 4096 blocks x ~6 tiles: amortizes the weight prologue and gives the
    // 3-deep pipeline enough iterations per block.
    const int eGrid = 4096;

    swizzle_weights<<<14, 256, 0, stream>>>(eW1, eW2, eb1, eb2, w1s, w2s, wcs, bcs);

    if (ws_size >= needFused) {
        // u/v for ALL layers, laid out [node][NLAYERS][16]; single fused edge pass.
        ushort_t* u0 = uv0;
        ushort_t* v0 = u0 + (size_t)NLAYERS * uvLayer;
        ln_uv<<<lnGrid, 256, 0, stream>>>(s_in, out_s, lnw, lnb, w1s,
                                          u0, v0, 0, NLAYERS, NLAYERS);
        edge_fused<NLAYERS><<<eGrid, 256, 0, stream>>>(ea_in, out_ea, ei, u0, v0,
                                                       w1s, w2s, wcs, bcs,
                                                       eb1, eb2, 0);
    } else {
        // Minimal ws: per-layer u/v slot ([node][1][16]), ea fp32 in-place.
        // NL=1 never touches wcs/bcs (no composite layers).
        ushort_t* u0 = uv0;
        ushort_t* v0 = u0 + uvLayer;
        for (int l = 0; l < NLAYERS; ++l) {
            ln_uv<<<lnGrid, 256, 0, stream>>>(l == 0 ? s_in : out_s, out_s,
                                              lnw, lnb, w1s, u0, v0, l, l + 1, 1);
            edge_fused<1><<<eGrid, 256, 0, stream>>>(
                l == 0 ? ea_in : (const float*)out_ea, out_ea, ei, u0, v0,
                w1s, w2s, wcs, bcs, eb1, eb2, l);
        }
    }
}